// Round 1
// baseline (511.631 us; speedup 1.0000x reference)
//
#include <hip/hip_runtime.h>
#include <stdint.h>

// ---------------- workspace layout (uint32 words), per matrix ----------------
#define OFF_H1     0u
#define OFF_H2     2048u
#define OFF_H3     4096u
#define OFF_PREFIX 6144u
#define OFF_RANK   6145u
#define OFF_T      6146u
#define OFF_E      6147u
#define OFF_Q      6148u
#define OFF_C      6149u
#define OFF_CNT    6150u
#define OFF_BUF    6160u          // pairs (idx, u), CAP entries
#define CAP        16384u
#define MAT_WORDS  (6160u + 2u * CAP)   // 38928 words ~152 KB; x2 matrices ~304 KB of ws
#define SUB        4              // LDS sub-histograms to reduce same-address atomic serialization

// Zero hist + state for both matrices (ws is re-poisoned 0xAA before every launch).
__global__ void init_k(uint32_t* __restrict__ ws) {
  uint32_t i = blockIdx.x * blockDim.x + threadIdx.x;
  if (i < 6160u) { ws[i] = 0u; ws[MAT_WORDS + i] = 0u; }
}

template <int PASS>
__global__ void hist_k(const float* __restrict__ A, const float* __restrict__ B,
                       uint32_t* __restrict__ ws, int nvec) {
  const int m = blockIdx.y;
  const float4* __restrict__ src = (const float4*)(m == 0 ? A : B);
  uint32_t* W = ws + (size_t)m * MAT_WORDS;
  __shared__ uint32_t h[2048 * SUB];
  for (int i = threadIdx.x; i < 2048 * SUB; i += blockDim.x) h[i] = 0u;
  uint32_t prefix = 0u;
  if (PASS > 1) prefix = W[OFF_PREFIX];   // written by preceding scan kernel (same stream)
  __syncthreads();
  const uint32_t sub = threadIdx.x & (SUB - 1);
  int idx0 = blockIdx.x * blockDim.x + threadIdx.x;
  int stride = gridDim.x * blockDim.x;
  for (int i = idx0; i < nvec; i += stride) {
    float4 f = src[i];
    const float v[4] = {f.x, f.y, f.z, f.w};
#pragma unroll
    for (int c = 0; c < 4; c++) {
      uint32_t u = __float_as_uint(v[c]) & 0x7fffffffu;  // bits of |x|, monotone as uint
      if (PASS == 1) {
        atomicAdd(&h[(u >> 21) * SUB + sub], 1u);
      } else if (PASS == 2) {
        if ((u >> 21) == (prefix >> 21))
          atomicAdd(&h[((u >> 10) & 2047u) * SUB + sub], 1u);
      } else {
        if ((u >> 10) == (prefix >> 10)) {
          atomicAdd(&h[(u & 1023u) * SUB + sub], 1u);
          // collect candidate (idx, u) for exact tie resolution later
          uint32_t slot = atomicAdd(&W[OFF_CNT], 1u);
          if (slot < CAP) {
            W[OFF_BUF + 2u * slot]      = (uint32_t)i * 4u + (uint32_t)c;
            W[OFF_BUF + 2u * slot + 1u] = u;
          }
        }
      }
    }
  }
  __syncthreads();
  uint32_t* gh = W + (PASS == 1 ? OFF_H1 : (PASS == 2 ? OFF_H2 : OFF_H3));
  for (int b = threadIdx.x; b < 2048; b += blockDim.x) {
    uint32_t s = 0u;
#pragma unroll
    for (int k = 0; k < SUB; k++) s += h[b * SUB + k];
    if (s) atomicAdd(&gh[b], s);
  }
}

// One block per matrix (blockIdx.x = m), 256 threads. Finds the bin containing
// rank r, updates prefix/rank; pass 3 finalizes T, E, q.
template <int PASS>
__global__ void scan_k(uint32_t* __restrict__ ws, uint32_t j) {
  const int m = blockIdx.x;
  uint32_t* W = ws + (size_t)m * MAT_WORDS;
  const uint32_t* hist = W + (PASS == 1 ? OFF_H1 : (PASS == 2 ? OFF_H2 : OFF_H3));
  __shared__ uint32_t h[2048];
  __shared__ uint32_t ps[256];
  const int t = threadIdx.x;
  // Load state BEFORE any barrier; __syncthreads (waitcnt+barrier) orders these
  // loads before the find-loop's stores.
  uint32_t r = (PASS == 1) ? j : W[OFF_RANK];
  uint32_t prefix = (PASS == 1) ? 0u : W[OFF_PREFIX];
  uint32_t s = 0u;
  for (int k = 0; k < 8; k++) {
    int b = t * 8 + k;
    uint32_t v = hist[b];
    h[b] = v;
    s += v;
  }
  ps[t] = s;
  __syncthreads();
  for (int off = 1; off < 256; off <<= 1) {
    uint32_t v = (t >= off) ? ps[t - off] : 0u;
    __syncthreads();
    ps[t] += v;
    __syncthreads();
  }
  uint32_t base = (t == 0) ? 0u : ps[t - 1];
  for (int k = 0; k < 8; k++) {
    int b = t * 8 + k;
    uint32_t c = h[b];
    if (r >= base && r < base + c) {   // exactly one (thread, bin) matches
      if (PASS == 1) {
        W[OFF_PREFIX] = (uint32_t)b << 21;
        W[OFF_RANK]   = r - base;
      } else if (PASS == 2) {
        W[OFF_PREFIX] = prefix | ((uint32_t)b << 10);
        W[OFF_RANK]   = r - base;
      } else {
        uint32_t T = prefix | (uint32_t)b;
        uint32_t p = r - base;         // position of rank-j inside equal range
        uint32_t E = c;                // exact multiplicity of T
        W[OFF_T] = T;
        W[OFF_E] = E;
        W[OFF_Q] = E - p;              // number of tied entries to set to 1
      }
    }
    base += c;
  }
}

// One block per matrix. Among buffered candidates with u == T, find cutoff
// index C = (E-q)-th smallest index; entries with idx >= C get 1 (q of them).
__global__ void tiesel_k(uint32_t* __restrict__ ws) {
  const int m = blockIdx.x;
  uint32_t* W = ws + (size_t)m * MAT_WORDS;
  uint32_t T = W[OFF_T];
  uint32_t E = W[OFF_E];
  uint32_t q = W[OFF_Q];
  uint32_t cnt = W[OFF_CNT];
  if (cnt > CAP) cnt = CAP;            // 16x headroom on expected ~1K; see notes
  uint32_t target = E - q;             // = p, in [0, E)
  __shared__ uint32_t res;
  if (threadIdx.x == 0) res = 0xFFFFFFFFu;
  __syncthreads();
  for (uint32_t c = threadIdx.x; c < cnt; c += blockDim.x) {
    if (W[OFF_BUF + 2u * c + 1u] != T) continue;
    uint32_t xi = W[OFF_BUF + 2u * c];
    uint32_t lt = 0u;
    for (uint32_t k = 0; k < cnt; k++) {
      if (W[OFF_BUF + 2u * k + 1u] == T && W[OFF_BUF + 2u * k] < xi) lt++;
    }
    if (lt == target) res = xi;        // unique: flat indices are distinct
  }
  __syncthreads();
  if (threadIdx.x == 0) W[OFF_C] = res;
}

__global__ void mask_k(const float* __restrict__ A, const float* __restrict__ B,
                       float* __restrict__ out, const uint32_t* __restrict__ ws,
                       int nvec, int n) {
  const int m = blockIdx.y;
  const float4* __restrict__ src = (const float4*)(m == 0 ? A : B);
  float4* __restrict__ dst = (float4*)(out + (size_t)m * (size_t)n);
  const uint32_t* W = ws + (size_t)m * MAT_WORDS;
  const uint32_t T = W[OFF_T];
  const uint32_t C = W[OFF_C];
  int idx0 = blockIdx.x * blockDim.x + threadIdx.x;
  int stride = gridDim.x * blockDim.x;
  for (int i = idx0; i < nvec; i += stride) {
    float4 f = src[i];
    const float v[4] = {f.x, f.y, f.z, f.w};
    float r[4];
#pragma unroll
    for (int c = 0; c < 4; c++) {
      uint32_t u = __float_as_uint(v[c]) & 0x7fffffffu;
      uint32_t idx = (uint32_t)i * 4u + (uint32_t)c;
      r[c] = (u > T || (u == T && idx >= C)) ? 1.0f : 0.0f;
    }
    dst[i] = make_float4(r[0], r[1], r[2], r[3]);
  }
}

extern "C" void kernel_launch(void* const* d_in, const int* in_sizes, int n_in,
                              void* d_out, int out_size, void* d_ws, size_t ws_size,
                              hipStream_t stream) {
  const float* A = (const float*)d_in[0];
  const float* B = (const float*)d_in[1];
  float* out = (float*)d_out;
  uint32_t* ws = (uint32_t*)d_ws;
  const int n = in_sizes[0];       // 16777216 for both matrices
  const int nvec = n / 4;
  // Matches Python: int((1.0 - 0.1) * n) in IEEE double, truncated.
  const uint32_t j = (uint32_t)((1.0 - 0.1) * (double)n);

  init_k<<<(6160 + 255) / 256, 256, 0, stream>>>(ws);

  dim3 hgrid(1024, 2);
  hist_k<1><<<hgrid, 256, 0, stream>>>(A, B, ws, nvec);
  scan_k<1><<<2, 256, 0, stream>>>(ws, j);
  hist_k<2><<<hgrid, 256, 0, stream>>>(A, B, ws, nvec);
  scan_k<2><<<2, 256, 0, stream>>>(ws, j);
  hist_k<3><<<hgrid, 256, 0, stream>>>(A, B, ws, nvec);
  scan_k<3><<<2, 256, 0, stream>>>(ws, j);
  tiesel_k<<<2, 256, 0, stream>>>(ws);
  mask_k<<<dim3(2048, 2), 256, 0, stream>>>(A, B, out, ws, nvec, n);
}

// Round 2
// 334.937 us; speedup vs baseline: 1.5275x; 1.5275x over previous
//
#include <hip/hip_runtime.h>
#include <stdint.h>

// ---------------- workspace layout (uint32 words), per matrix ----------------
#define OFF_H1     0u        // 2048 bins, bits 30..21 (10 used)
#define OFF_H2     2048u     // 2048 bins, bits 20..10
#define OFF_H3     4096u     // 1024 bins, bits 9..0
#define OFF_PREFIX 6144u
#define OFF_RANK   6145u
#define OFF_T      6146u
#define OFF_C      6147u
#define OFF_CNT    6148u     // tie-candidate count (22-bit prefix matches)
#define OFF_BCNT   6656u     // 512 per-segment counts (written unconditionally)
#define OFF_BUF    7168u     // tie candidates (idx,u) pairs
#define CAP        8192u     // expected ~1024 -> 8x headroom
#define MAT_WORDS  (7168u + 2u * CAP)   // 23552 words ~92KB; x2 well under round-1's 311KB
#define SUB        4         // LDS sub-histograms vs same-address atomic serialization
#define NB2        512       // pass-2 blocks per matrix (= segments)
#define SEGCAP     16384u    // entries per segment; expected ~4100 -> 4x headroom
// segment buffer lives in d_out: matrix m at out_u32 + m*16777216 words (64MiB half,
// 512*16384*2 words = exactly 64MiB). mask_k overwrites d_out afterwards.

__global__ void init_k(uint32_t* __restrict__ ws) {
  uint32_t i = blockIdx.x * blockDim.x + threadIdx.x;
  if (i < 6656u) { ws[i] = 0u; ws[MAT_WORDS + i] = 0u; }
}

// PASS 1: full-scan histogram of bits 30..21.
__global__ void hist1_k(const float* __restrict__ A, const float* __restrict__ B,
                        uint32_t* __restrict__ ws, int nvec) {
  const int m = blockIdx.y;
  const float4* __restrict__ src = (const float4*)(m == 0 ? A : B);
  uint32_t* W = ws + (size_t)m * MAT_WORDS;
  __shared__ uint32_t h[2048 * SUB];
  for (int i = threadIdx.x; i < 2048 * SUB; i += blockDim.x) h[i] = 0u;
  __syncthreads();
  const uint32_t sub = threadIdx.x & (SUB - 1);
  int idx0 = blockIdx.x * blockDim.x + threadIdx.x;
  int stride = gridDim.x * blockDim.x;
  for (int i = idx0; i < nvec; i += stride) {
    float4 f = src[i];
    const float v[4] = {f.x, f.y, f.z, f.w};
#pragma unroll
    for (int c = 0; c < 4; c++) {
      uint32_t u = __float_as_uint(v[c]) & 0x7fffffffu;
      atomicAdd(&h[(u >> 21) * SUB + sub], 1u);
    }
  }
  __syncthreads();
  uint32_t* gh = W + OFF_H1;
  for (int b = threadIdx.x; b < 2048; b += blockDim.x) {
    uint32_t s = 0u;
#pragma unroll
    for (int k = 0; k < SUB; k++) s += h[b * SUB + k];
    if (s) atomicAdd(&gh[b], s);
  }
}

// PASS 2: full-scan; histogram bits 20..10 of 10-bit-prefix matches AND collect
// matched (idx,u) pairs into this block's private segment of d_out.
__global__ void hist2_k(const float* __restrict__ A, const float* __restrict__ B,
                        uint32_t* __restrict__ ws, uint32_t* __restrict__ outbuf,
                        int nvec) {
  const int m = blockIdx.y;
  const float4* __restrict__ src = (const float4*)(m == 0 ? A : B);
  uint32_t* W = ws + (size_t)m * MAT_WORDS;
  uint32_t* seg = outbuf + (size_t)m * 16777216u + (size_t)blockIdx.x * (SEGCAP * 2u);
  __shared__ uint32_t h[2048 * SUB];
  __shared__ uint32_t segn;
  for (int i = threadIdx.x; i < 2048 * SUB; i += blockDim.x) h[i] = 0u;
  if (threadIdx.x == 0) segn = 0u;
  uint32_t prefix = W[OFF_PREFIX];
  __syncthreads();
  const uint32_t sub = threadIdx.x & (SUB - 1);
  int idx0 = blockIdx.x * blockDim.x + threadIdx.x;
  int stride = gridDim.x * blockDim.x;
  for (int i = idx0; i < nvec; i += stride) {
    float4 f = src[i];
    const float v[4] = {f.x, f.y, f.z, f.w};
#pragma unroll
    for (int c = 0; c < 4; c++) {
      uint32_t u = __float_as_uint(v[c]) & 0x7fffffffu;
      if ((u >> 21) == (prefix >> 21)) {
        atomicAdd(&h[((u >> 10) & 2047u) * SUB + sub], 1u);
        uint32_t s = atomicAdd(&segn, 1u);
        if (s < SEGCAP) { seg[2u * s] = (uint32_t)i * 4u + (uint32_t)c; seg[2u * s + 1u] = u; }
      }
    }
  }
  __syncthreads();
  uint32_t* gh = W + OFF_H2;
  for (int b = threadIdx.x; b < 2048; b += blockDim.x) {
    uint32_t s = 0u;
#pragma unroll
    for (int k = 0; k < SUB; k++) s += h[b * SUB + k];
    if (s) atomicAdd(&gh[b], s);
  }
  if (threadIdx.x == 0) {
    uint32_t s = segn; if (s > SEGCAP) s = SEGCAP;
    W[OFF_BCNT + blockIdx.x] = s;
  }
}

// Scan for passes 1 and 2: find bin containing rank r, update prefix/rank.
template <int PASS>
__global__ void scan_k(uint32_t* __restrict__ ws, uint32_t j) {
  const int m = blockIdx.x;
  uint32_t* W = ws + (size_t)m * MAT_WORDS;
  const uint32_t* hist = W + (PASS == 1 ? OFF_H1 : OFF_H2);
  __shared__ uint32_t h[2048];
  __shared__ uint32_t ps[256];
  const int t = threadIdx.x;
  uint32_t r = (PASS == 1) ? j : W[OFF_RANK];
  uint32_t prefix = (PASS == 1) ? 0u : W[OFF_PREFIX];
  uint32_t s = 0u;
  for (int k = 0; k < 8; k++) {
    int b = t * 8 + k;
    uint32_t v = hist[b];
    h[b] = v;
    s += v;
  }
  ps[t] = s;
  __syncthreads();
  for (int off = 1; off < 256; off <<= 1) {
    uint32_t v = (t >= off) ? ps[t - off] : 0u;
    __syncthreads();
    ps[t] += v;
    __syncthreads();
  }
  uint32_t base = (t == 0) ? 0u : ps[t - 1];
  for (int k = 0; k < 8; k++) {
    int b = t * 8 + k;
    uint32_t c = h[b];
    if (r >= base && r < base + c) {          // exactly one (thread,bin) matches
      if (PASS == 1) W[OFF_PREFIX] = (uint32_t)b << 21;
      else           W[OFF_PREFIX] = prefix | ((uint32_t)b << 10);
      W[OFF_RANK] = r - base;
    }
    base += c;
  }
}

// PASS 3 over the segment buffer only (~17MB instead of 256MB): histogram low
// 10 bits of 21-bit-prefix matches; collect exact tie candidates into ws.
__global__ void pass3_k(uint32_t* __restrict__ ws, const uint32_t* __restrict__ outbuf) {
  const int m = blockIdx.y;
  uint32_t* W = ws + (size_t)m * MAT_WORDS;
  const uint32_t* seg = outbuf + (size_t)m * 16777216u + (size_t)blockIdx.x * (SEGCAP * 2u);
  __shared__ uint32_t h[1024];
  for (int i = threadIdx.x; i < 1024; i += blockDim.x) h[i] = 0u;
  uint32_t n = W[OFF_BCNT + blockIdx.x];
  uint32_t prefix = W[OFF_PREFIX];
  __syncthreads();
  for (uint32_t e = threadIdx.x; e < n; e += blockDim.x) {
    uint32_t idx = seg[2u * e];
    uint32_t u   = seg[2u * e + 1u];
    if ((u >> 10) == (prefix >> 10)) {
      atomicAdd(&h[u & 1023u], 1u);
      uint32_t slot = atomicAdd(&W[OFF_CNT], 1u);     // ~1024 total per matrix
      if (slot < CAP) { W[OFF_BUF + 2u * slot] = idx; W[OFF_BUF + 2u * slot + 1u] = u; }
    }
  }
  __syncthreads();
  for (int b = threadIdx.x; b < 1024; b += blockDim.x)
    if (h[b]) atomicAdd(&W[OFF_H3 + b], h[b]);
}

// Fused: scan pass-3 histogram -> T, then tie-resolve entirely in LDS.
__global__ void scan3tie_k(uint32_t* __restrict__ ws) {
  const int m = blockIdx.x;
  uint32_t* W = ws + (size_t)m * MAT_WORDS;
  __shared__ uint32_t h[1024];
  __shared__ uint32_t ps[256];
  __shared__ uint32_t sT, sTarget;
  __shared__ uint32_t tie_idx[1024];
  __shared__ uint32_t tie_n;
  const int t = threadIdx.x;
  uint32_t r = W[OFF_RANK];
  uint32_t prefix = W[OFF_PREFIX];
  uint32_t cnt = W[OFF_CNT]; if (cnt > CAP) cnt = CAP;
  if (t == 0) tie_n = 0u;
  uint32_t s = 0u;
  for (int k = 0; k < 4; k++) {
    int b = t * 4 + k;
    uint32_t v = W[OFF_H3 + b];
    h[b] = v;
    s += v;
  }
  ps[t] = s;
  __syncthreads();
  for (int off = 1; off < 256; off <<= 1) {
    uint32_t v = (t >= off) ? ps[t - off] : 0u;
    __syncthreads();
    ps[t] += v;
    __syncthreads();
  }
  uint32_t base = (t == 0) ? 0u : ps[t - 1];
  for (int k = 0; k < 4; k++) {
    int b = t * 4 + k;
    uint32_t c = h[b];
    if (r >= base && r < base + c) { sT = prefix | (uint32_t)b; sTarget = r - base; }
    base += c;
  }
  __syncthreads();
  const uint32_t T = sT, target = sTarget;   // target = p; q = E - p entries get 1
  for (uint32_t c2 = t; c2 < cnt; c2 += 256u) {
    if (W[OFF_BUF + 2u * c2 + 1u] == T) {
      uint32_t slot = atomicAdd(&tie_n, 1u);
      if (slot < 1024u) tie_idx[slot] = W[OFF_BUF + 2u * c2];
    }
  }
  __syncthreads();
  uint32_t E2 = tie_n; if (E2 > 1024u) E2 = 1024u;
  for (uint32_t c2 = t; c2 < E2; c2 += 256u) {
    uint32_t xi = tie_idx[c2];
    uint32_t lt = 0u;
    for (uint32_t k2 = 0; k2 < E2; k2++) lt += (tie_idx[k2] < xi) ? 1u : 0u;
    if (lt == target) W[OFF_C] = xi;          // p-th smallest index = cutoff
  }
  if (t == 0) W[OFF_T] = T;
}

__global__ void mask_k(const float* __restrict__ A, const float* __restrict__ B,
                       float* __restrict__ out, const uint32_t* __restrict__ ws,
                       int nvec, int n) {
  const int m = blockIdx.y;
  const float4* __restrict__ src = (const float4*)(m == 0 ? A : B);
  float4* __restrict__ dst = (float4*)(out + (size_t)m * (size_t)n);
  const uint32_t* W = ws + (size_t)m * MAT_WORDS;
  const uint32_t T = W[OFF_T];
  const uint32_t C = W[OFF_C];
  int idx0 = blockIdx.x * blockDim.x + threadIdx.x;
  int stride = gridDim.x * blockDim.x;
  for (int i = idx0; i < nvec; i += stride) {
    float4 f = src[i];
    const float v[4] = {f.x, f.y, f.z, f.w};
    float r[4];
#pragma unroll
    for (int c = 0; c < 4; c++) {
      uint32_t u = __float_as_uint(v[c]) & 0x7fffffffu;
      uint32_t idx = (uint32_t)i * 4u + (uint32_t)c;
      r[c] = (u > T || (u == T && idx >= C)) ? 1.0f : 0.0f;
    }
    dst[i] = make_float4(r[0], r[1], r[2], r[3]);
  }
}

extern "C" void kernel_launch(void* const* d_in, const int* in_sizes, int n_in,
                              void* d_out, int out_size, void* d_ws, size_t ws_size,
                              hipStream_t stream) {
  const float* A = (const float*)d_in[0];
  const float* B = (const float*)d_in[1];
  float* out = (float*)d_out;
  uint32_t* ws = (uint32_t*)d_ws;
  uint32_t* outbuf = (uint32_t*)d_out;     // scratch until mask_k overwrites it
  const int n = in_sizes[0];               // 16777216 for both matrices
  const int nvec = n / 4;
  const uint32_t j = (uint32_t)((1.0 - 0.1) * (double)n);   // == Python int((1-k)*n)

  init_k<<<(6656 + 255) / 256, 256, 0, stream>>>(ws);
  hist1_k<<<dim3(1024, 2), 256, 0, stream>>>(A, B, ws, nvec);
  scan_k<1><<<2, 256, 0, stream>>>(ws, j);
  hist2_k<<<dim3(NB2, 2), 256, 0, stream>>>(A, B, ws, outbuf, nvec);
  scan_k<2><<<2, 256, 0, stream>>>(ws, j);
  pass3_k<<<dim3(NB2, 2), 256, 0, stream>>>(ws, outbuf);
  scan3tie_k<<<2, 256, 0, stream>>>(ws);
  mask_k<<<dim3(2048, 2), 256, 0, stream>>>(A, B, out, ws, nvec, n);
}